// Round 7
// baseline (647.702 us; speedup 1.0000x reference)
//
#include <hip/hip_runtime.h>
#include <math.h>

#define FH 160
#define FW 160
#define NPOS (FH*FW)        // 25600
#define NANCH (NPOS*9)      // 230400
#define IMG 2560.0f
#define STRIDE 16.0f
#define NBLK 400            // heads grid; must match launch + barrier target

typedef __attribute__((ext_vector_type(8))) _Float16 half8;
typedef __attribute__((ext_vector_type(4))) float f32x4;
typedef unsigned long long u64;

__device__ __forceinline__ unsigned short f2h(float v) {
    _Float16 h = (_Float16)v;          // RNE
    return *(unsigned short*)&h;
}
__device__ __forceinline__ void g2l16(void* lds, const void* g) {
    __builtin_amdgcn_global_load_lds(
        (const __attribute__((address_space(1))) void*)g,
        (__attribute__((address_space(3))) void*)lds, 16, 0, 0);
}
__device__ __forceinline__ u64 pack_key(float s, int n) {
    unsigned int bu = __float_as_uint(s);
    unsigned int key = (bu & 0x80000000u) ? ~bu : (bu | 0x80000000u);
    return ((u64)key << 32) | (unsigned int)~(unsigned int)n;
}
__device__ __forceinline__ u64 wave_max64(u64 v) {
#pragma unroll
    for (int off = 32; off > 0; off >>= 1) {
        u64 o = __shfl_xor(v, off, 64);
        v = v > o ? v : o;
    }
    return v;
}
// software grid barrier: device-scope counter, agent fences. Safe here:
// heads runs alone (sequential graph), 400 blocks x 24.6KB LDS all resident.
__device__ __forceinline__ void gbar(unsigned* cnt, int phase) {
    __syncthreads();
    if (threadIdx.x == 0) {
        __threadfence();   // release: own block's stores visible device-wide
        __hip_atomic_fetch_add(cnt, 1u, __ATOMIC_RELAXED,
                               __HIP_MEMORY_SCOPE_AGENT);
        while (__hip_atomic_load(cnt, __ATOMIC_RELAXED,
                                 __HIP_MEMORY_SCOPE_AGENT)
               < (unsigned)(NBLK*phase))
            __builtin_amdgcn_s_sleep(8);
    }
    __syncthreads();
    __threadfence();       // acquire: see other blocks' stores
}

// ---------------------------------------------------------------------------
// prep: fused — features pad+fp16 [162][162][512]; conv1 W transpose to
// [512 oc][4608 k] fp16; head W pack to [128 u][512 c] fp16.
// Also zeroes the heads grid-barrier counter (ws is 0xAA-poisoned per call).
// ---------------------------------------------------------------------------
__global__ __launch_bounds__(256) void prep_kernel(
    const float* __restrict__ f, const float* __restrict__ w,
    const float* __restrict__ regw, const float* __restrict__ clsw,
    const float* __restrict__ lmw,
    unsigned short* __restrict__ fph, unsigned short* __restrict__ wt,
    unsigned short* __restrict__ wh, unsigned* __restrict__ cnt)
{
    __shared__ float tile[32][33];
    const int bid = blockIdx.x, t = threadIdx.x;
    if (bid == 0 && t == 0) *cnt = 0u;
    if (bid < 13122) {                      // features: 162*162*128 threads
        int idx = bid*256 + t;
        int c4 = (idx & 127) << 2;
        int rest = idx >> 7;
        int x = rest % 162, y = rest / 162;
        float4 v = make_float4(0.f, 0.f, 0.f, 0.f);
        if (y > 0 && y < 161 && x > 0 && x < 161)
            v = *(const float4*)(f + ((size_t)((y-1)*FW + (x-1)) << 9) + c4);
        ushort4 h;
        h.x = f2h(v.x); h.y = f2h(v.y); h.z = f2h(v.z); h.w = f2h(v.w);
        *(ushort4*)(fph + ((size_t)(y*162 + x) << 9) + c4) = h;
    } else if (bid < 15426) {               // conv1 W: 144 x 16 transpose tiles
        int b = bid - 13122;
        int k0 = (b % 144)*32, oc0 = (b / 144)*32;
        int c = t & 31, r8 = t >> 5;
#pragma unroll
        for (int i = 0; i < 4; ++i) {
            int r = r8 + i*8;
            tile[c][r] = w[(size_t)(k0 + r)*512 + oc0 + c];
        }
        __syncthreads();
#pragma unroll
        for (int i = 0; i < 4; ++i) {
            int orow = r8 + i*8, kcol = c;
            wt[(size_t)(oc0 + orow)*4608 + k0 + kcol] = f2h(tile[orow][kcol]);
        }
    } else {                                // head W pack: 128x512
        int i = (bid - 15426)*256 + t;
        int u = i >> 9, c = i & 511;
        float v = 0.f;
        if (u < 36)      v = regw[c*72 + (u>>2)*8 + (u&3)];
        else if (u < 45) v = clsw[c*9 + (u-36)];
        else if (u < 99) v = lmw[c*54 + (u-45)];
        wh[i] = f2h(v);
    }
}

// ---------------------------------------------------------------------------
// conv1 MFMA fp16, BM=BN=128 BK=64, 256 thr (2x2 waves), wave tile 64x64.
// FROZEN since R5: 178 us = 35% of f16 ceiling = the documented m97-structure
// plateau (control rows for the bench).
// ---------------------------------------------------------------------------
__global__ __launch_bounds__(256) void conv1_mfma_kernel(
    const unsigned short* __restrict__ fph, const unsigned short* __restrict__ wt,
    const float* __restrict__ bias, unsigned short* __restrict__ xh)
{
    __shared__ unsigned short As[128*64];
    __shared__ unsigned short Bs[128*64];
    const int tid  = threadIdx.x;
    const int lane = tid & 63;
    const int wi   = (tid >> 7) & 1;
    const int wj   = (tid >> 6) & 1;
    const int bid  = blockIdx.x;
    const int xcd  = bid & 7, sl = bid >> 3;
    const int oc0  = (xcd & 3) * 128;
    const int pt   = (xcd >> 2) * 100 + sl;
    const int ty = pt / 5, tx = pt - ty*5;
    const int y0 = ty*4, x0 = tx*32;

    const int srow = tid >> 3;               // 0..31
    const int kswz = (((tid & 7) ^ (srow & 7)) << 3);
    const int quad = lane >> 4, fr = lane & 15;

    f32x4 acc[4][4] = {};
    const size_t bBase = (size_t)(oc0 + srow)*4608 + kswz;

    for (int tap = 0; tap < 9; ++tap) {
        const int ky = tap/3, kx = tap - (tap/3)*3;
        const size_t aBase = ((size_t)((y0 + ky)*162 + (x0 + srow + kx)) << 9) + kswz;
        const size_t bTap  = bBase + tap*512;
        for (int icb = 0; icb < 512; icb += 64) {
#pragma unroll
            for (int r = 0; r < 4; ++r) {
                g2l16(As + tid*8 + r*2048, fph + aBase + (size_t)r*162*512 + icb);
                g2l16(Bs + tid*8 + r*2048, wt  + bTap  + (size_t)r*32*4608 + icb);
            }
            __syncthreads();
#pragma unroll
            for (int kk = 0; kk < 2; ++kk) {
                const int sa = ((kk*4 + quad) ^ (fr & 7)) << 3;
                half8 a[4], b[4];
#pragma unroll
                for (int i = 0; i < 4; ++i) {
                    a[i] = *(const half8*)(As + (wi*64 + i*16 + fr)*64 + sa);
                    b[i] = *(const half8*)(Bs + (wj*64 + i*16 + fr)*64 + sa);
                }
#pragma unroll
                for (int i = 0; i < 4; ++i)
#pragma unroll
                    for (int j = 0; j < 4; ++j)
                        acc[i][j] = __builtin_amdgcn_mfma_f32_16x16x32_f16(a[i], b[j], acc[i][j], 0, 0, 0);
            }
            __syncthreads();
        }
    }

#pragma unroll
    for (int i = 0; i < 4; ++i) {
#pragma unroll
        for (int r = 0; r < 4; ++r) {
            int mi = wi*64 + i*16 + quad*4 + r;
            int p = (y0 + (mi >> 5))*FW + x0 + (mi & 31);
#pragma unroll
            for (int j = 0; j < 4; ++j) {
                int col = oc0 + wj*64 + j*16 + fr;
                float v = acc[i][j][r] + bias[col];
                xh[(size_t)p*512 + col] = f2h(v > 0.f ? v : 0.f);
            }
        }
    }
}

// ---------------------------------------------------------------------------
// heads MFMA fp16 (BM=64 -> 400 blocks for latency hiding) + fused decode
// + fused 6-round greedy NMS via software grid barrier. One dispatch does:
// GEMM -> deltas/cls/lm -> anchors/boxes/scores/blockmax -> NMS -> rois.
// ---------------------------------------------------------------------------
__global__ __launch_bounds__(256) void heads_mfma_kernel(
    const unsigned short* __restrict__ xh, const unsigned short* __restrict__ wh,
    const float* __restrict__ regb, const float* __restrict__ clsb,
    const float* __restrict__ lmb,
    float* __restrict__ lm_out, float* __restrict__ boxes,
    float* __restrict__ anch_out, float* __restrict__ s_arr,
    u64* __restrict__ blockmax, unsigned* __restrict__ cnt,
    float* __restrict__ rois)
{
    __shared__ union SM {
        struct { unsigned short As[64*64]; unsigned short Bs[128*64]; } g;
        struct { float sdel[64][40]; float scls[64][12]; u64 red[4]; } e;
    } sm;
    unsigned short* As = sm.g.As;
    unsigned short* Bs = sm.g.Bs;
    const int tid  = threadIdx.x;
    const int lane = tid & 63;
    const int wi   = (tid >> 7) & 1;     // m-half (32 rows)
    const int wj   = (tid >> 6) & 1;     // n-half (64 cols)
    const int p0   = blockIdx.x * 64;

    const int srow = tid >> 3;           // 0..31
    const int kswz = (((tid & 7) ^ (srow & 7)) << 3);
    const int quad = lane >> 4, fr = lane & 15;
    f32x4 acc[2][4] = {};

    const size_t aOfs = ((size_t)(p0 + srow) << 9) + kswz;
    const size_t bOfs = ((size_t)srow << 9) + kswz;

    for (int icb = 0; icb < 512; icb += 64) {
#pragma unroll
        for (int r = 0; r < 2; ++r)
            g2l16(As + tid*8 + r*2048, xh + aOfs + (size_t)r*32*512 + icb);
#pragma unroll
        for (int r = 0; r < 4; ++r)
            g2l16(Bs + tid*8 + r*2048, wh + bOfs + (size_t)r*32*512 + icb);
        __syncthreads();
#pragma unroll
        for (int kk = 0; kk < 2; ++kk) {
            const int sa = ((kk*4 + quad) ^ (fr & 7)) << 3;
            half8 a[2], b[4];
#pragma unroll
            for (int i = 0; i < 2; ++i)
                a[i] = *(const half8*)(As + (wi*32 + i*16 + fr)*64 + sa);
#pragma unroll
            for (int j = 0; j < 4; ++j)
                b[j] = *(const half8*)(Bs + (wj*64 + j*16 + fr)*64 + sa);
#pragma unroll
            for (int i = 0; i < 2; ++i)
#pragma unroll
                for (int j = 0; j < 4; ++j)
                    acc[i][j] = __builtin_amdgcn_mfma_f32_16x16x32_f16(a[i], b[j], acc[i][j], 0, 0, 0);
        }
        __syncthreads();
    }
    // GEMM done; LDS drained -> overlay epilogue structs.

#pragma unroll
    for (int i = 0; i < 2; ++i) {
#pragma unroll
        for (int r = 0; r < 4; ++r) {
            int pl = wi*32 + i*16 + quad*4 + r;
            int p = p0 + pl;
#pragma unroll
            for (int j = 0; j < 4; ++j) {
                int u = wj*64 + j*16 + fr;
                float v = acc[i][j][r];
                if (u < 36) {
                    sm.e.sdel[pl][u] = v + regb[(u>>2)*8 + (u&3)];
                } else if (u < 45) {
                    float z = v + clsb[u-36];
                    sm.e.scls[pl][u-36] = 1.f/(1.f + expf(-z));
                } else if (u < 99) {
                    lm_out[(size_t)p*54 + (u-45)] = v + lmb[u-45];
                }
            }
        }
    }
    __syncthreads();

    // fused decode: 64 positions x 9 anchors; local NMS seed max
    u64 local = 0ull;
    for (int t = tid; t < 64*9; t += 256) {
        int pl = t / 9, a = t - pl*9;
        int p = p0 + pl;
        int y = p / FW, x = p - FW*y;
        float cx = (x + 0.5f)*STRIDE, cy = (y + 0.5f)*STRIDE;
        const float rr[3] = {0.5f, 1.f, 2.f};
        const float ss[3] = {8.f, 16.f, 32.f};
        float r = rr[a/3], sv = ss[a - (a/3)*3];
        float h  = sqrtf(sv*sv/r)*STRIDE;
        float wvv = h * r;
        float x1a = cx - wvv*0.5f, y1a = cy - h*0.5f;
        float x2a = cx + wvv*0.5f, y2a = cy + h*0.5f;
        size_t n = (size_t)p*9 + a;
        float4 av = {x1a, y1a, x2a, y2a};
        *(float4*)(anch_out + 4*n) = av;
        bool valid = (x1a >= 0.f) && (y1a >= 0.f) && (x2a <= IMG) && (y2a <= IMG);

        float dx = sm.e.sdel[pl][a*4+0], dy = sm.e.sdel[pl][a*4+1];
        float dw = sm.e.sdel[pl][a*4+2], dh = sm.e.sdel[pl][a*4+3];
        float px = cx + wvv*dx, py = cy + h*dy;
        float pw = wvv*expf(dw), ph = h*expf(dh);
        float bx1 = px - pw*0.5f, by1 = py - ph*0.5f;
        float4 b;
        b.x = fminf(fmaxf(bx1, 0.f), IMG);
        b.y = fminf(fmaxf(by1, 0.f), IMG);
        b.z = fminf(fmaxf(bx1 + pw, 0.f), IMG);
        b.w = fminf(fmaxf(by1 + ph, 0.f), IMG);
        *(float4*)(boxes + 4*n) = b;
        float s = valid ? sm.e.scls[pl][a] : -1.f;
        s_arr[n] = s;
        u64 pk = pack_key(s, (int)n);
        local = local > pk ? local : pk;
    }
    local = wave_max64(local);
    if ((tid & 63) == 0) sm.e.red[tid >> 6] = local;
    __syncthreads();
    if (tid == 0) {
        u64 m = sm.e.red[0];
        m = m > sm.e.red[1] ? m : sm.e.red[1];
        m = m > sm.e.red[2] ? m : sm.e.red[2];
        m = m > sm.e.red[3] ? m : sm.e.red[3];
        __hip_atomic_store(&blockmax[blockIdx.x], m, __ATOMIC_RELAXED,
                           __HIP_MEMORY_SCOPE_AGENT);
    }

    // ---- fused greedy NMS: 6 winners, 5 suppression rounds ----
    for (int k = 1; k <= 6; ++k) {
        gbar(cnt, k);                       // blockmax of round k-1 visible
        u64 v = 0ull;
        for (int i = tid; i < NBLK; i += 256) {
            u64 x = __hip_atomic_load(&blockmax[i], __ATOMIC_RELAXED,
                                      __HIP_MEMORY_SCOPE_AGENT);
            v = v > x ? v : x;
        }
        v = wave_max64(v);
        if ((tid & 63) == 0) sm.e.red[tid >> 6] = v;
        __syncthreads();
        u64 m = sm.e.red[0];
        m = m > sm.e.red[1] ? m : sm.e.red[1];
        m = m > sm.e.red[2] ? m : sm.e.red[2];
        m = m > sm.e.red[3] ? m : sm.e.red[3];
        unsigned wn = ~(unsigned)(m & 0xFFFFFFFFull);
        if (blockIdx.x == 0 && tid == 0)
            *(float4*)(rois + 4*(k-1)) = *(const float4*)(boxes + (size_t)4*wn);
        if (k == 6) break;
        __syncthreads();                    // red WAR guard before reuse

        float4 wb = *(const float4*)(boxes + (size_t)4*wn);
        float wa = (wb.z - wb.x)*(wb.w - wb.y);
        u64 loc = 0ull;
        const int base = blockIdx.x * 576;
        for (int i2 = tid; i2 < 576; i2 += 256) {
            int n = base + i2;
            float s = s_arr[n];
            float4 b = *(const float4*)(boxes + (size_t)4*n);
            float ix = fminf(wb.z, b.z) - fmaxf(wb.x, b.x);
            float iy = fminf(wb.w, b.w) - fmaxf(wb.y, b.y);
            float inter = fmaxf(ix, 0.f)*fmaxf(iy, 0.f);
            float a2 = (b.z - b.x)*(b.w - b.y);
            float iou = inter/(wa + a2 - inter + 1e-9f);
            if (iou > 0.5f && s > -1.f) { s = -1.f; s_arr[n] = -1.f; }
            u64 pk = pack_key(s, n);
            loc = loc > pk ? loc : pk;
        }
        loc = wave_max64(loc);
        if ((tid & 63) == 0) sm.e.red[tid >> 6] = loc;
        __syncthreads();
        if (tid == 0) {
            u64 mm = sm.e.red[0];
            mm = mm > sm.e.red[1] ? mm : sm.e.red[1];
            mm = mm > sm.e.red[2] ? mm : sm.e.red[2];
            mm = mm > sm.e.red[3] ? mm : sm.e.red[3];
            __hip_atomic_store(&blockmax[blockIdx.x], mm, __ATOMIC_RELAXED,
                               __HIP_MEMORY_SCOPE_AGENT);
        }
    }
}

// ---------------------------------------------------------------------------
// fallback fp32 path kernels (known-good round-1 structure)
// ---------------------------------------------------------------------------
__global__ __launch_bounds__(256) void conv1_kernel(
    const float* __restrict__ f, const float* __restrict__ w,
    const float* __restrict__ bias, float* __restrict__ xout)
{
    __shared__ float As2[32][66];
    __shared__ float Bs2[32][66];
    const int tid = threadIdx.x;
    const int nt = blockIdx.x;
    const int mt = blockIdx.y;
    const int p0 = mt*64, oc0 = nt*64;
    const int tm = tid & 15, tn = tid >> 4;
    const int kA = tid & 31, mA = tid >> 5;
    const int nB = tid & 63, kB = tid >> 6;
    int yv[8], xv[8];
#pragma unroll
    for (int it = 0; it < 8; ++it) {
        int p = p0 + mA + it*8;
        yv[it] = p / FW;
        xv[it] = p - yv[it]*FW;
    }
    float acc[4][4] = {};
    for (int tap = 0; tap < 9; ++tap) {
        const int ky = tap/3 - 1, kx = tap%3 - 1;
        for (int icb = 0; icb < 512; icb += 32) {
#pragma unroll
            for (int it = 0; it < 8; ++it) {
                int yy = yv[it] + ky, xx = xv[it] + kx;
                float v = 0.f;
                if ((unsigned)yy < (unsigned)FH && (unsigned)xx < (unsigned)FW)
                    v = f[(((yy*FW)+xx)<<9) + icb + kA];
                As2[kA][mA + it*8] = v;
            }
            const float* wp = w + ((size_t)(tap*512 + icb + kB))*512 + oc0 + nB;
#pragma unroll
            for (int it = 0; it < 8; ++it)
                Bs2[kB + it*4][nB] = wp[(size_t)it*4*512];
            __syncthreads();
#pragma unroll 8
            for (int kk = 0; kk < 32; ++kk) {
                float a0 = As2[kk][4*tm+0], a1 = As2[kk][4*tm+1],
                      a2 = As2[kk][4*tm+2], a3 = As2[kk][4*tm+3];
                float b0 = Bs2[kk][4*tn+0], b1 = Bs2[kk][4*tn+1],
                      b2 = Bs2[kk][4*tn+2], b3 = Bs2[kk][4*tn+3];
                acc[0][0] += a0*b0; acc[0][1] += a0*b1; acc[0][2] += a0*b2; acc[0][3] += a0*b3;
                acc[1][0] += a1*b0; acc[1][1] += a1*b1; acc[1][2] += a1*b2; acc[1][3] += a1*b3;
                acc[2][0] += a2*b0; acc[2][1] += a2*b1; acc[2][2] += a2*b2; acc[2][3] += a2*b3;
                acc[3][0] += a3*b0; acc[3][1] += a3*b1; acc[3][2] += a3*b2; acc[3][3] += a3*b3;
            }
            __syncthreads();
        }
    }
#pragma unroll
    for (int i = 0; i < 4; ++i) {
        int p = p0 + 4*tm + i;
        float4 o;
        float* op = &o.x;
#pragma unroll
        for (int j = 0; j < 4; ++j) {
            float v = acc[i][j] + bias[oc0 + 4*tn + j];
            op[j] = v > 0.f ? v : 0.f;
        }
        *(float4*)(xout + (size_t)p*512 + oc0 + 4*tn) = o;
    }
}

__global__ __launch_bounds__(256) void wprep_kernel(
    const float* __restrict__ regw, const float* __restrict__ clsw,
    const float* __restrict__ lmw, float* __restrict__ wT)
{
    int i = blockIdx.x*256 + threadIdx.x;
    if (i >= 99*512) return;
    int u = i >> 9, c = i & 511;
    float v;
    if (u < 36)      v = regw[c*72 + (u>>2)*8 + (u&3)];
    else if (u < 45) v = clsw[c*9 + (u-36)];
    else             v = lmw[c*54 + (u-45)];
    wT[i] = v;
}

__global__ __launch_bounds__(256) void heads_kernel(
    const float* __restrict__ x, const float* __restrict__ wT,
    const float* __restrict__ regb, const float* __restrict__ clsb,
    const float* __restrict__ lmb,
    float* __restrict__ lm_out, float* __restrict__ deltas,
    float* __restrict__ s_arr)
{
    __shared__ float xs[16*516];
    const int p0 = blockIdx.x * 16;
    const float4* src = (const float4*)(x + (size_t)p0*512);
    for (int i = threadIdx.x; i < 16*128; i += 256) {
        int row = i >> 7, c4 = i & 127;
        *(float4*)(xs + row*516 + c4*4) = src[row*128 + c4];
    }
    __syncthreads();
    for (int oi = threadIdx.x; oi < 99*16; oi += 256) {
        int ps = oi & 15, u = oi >> 4;
        const float4* wv = (const float4*)(wT + (u << 9));
        const float4* xv = (const float4*)(xs + ps*516);
        float acc = 0.f;
#pragma unroll 4
        for (int c = 0; c < 128; ++c) {
            float4 a = xv[c], b = wv[c];
            acc += a.x*b.x + a.y*b.y + a.z*b.z + a.w*b.w;
        }
        int p = p0 + ps;
        if (u < 36) {
            int aidx = u >> 2, r = u & 3;
            deltas[(size_t)(p*9 + aidx)*4 + r] = acc + regb[aidx*8 + r];
        } else if (u < 45) {
            float z = acc + clsb[u-36];
            s_arr[p*9 + (u-36)] = 1.f/(1.f + expf(-z));
        } else {
            lm_out[(size_t)p*54 + (u-45)] = acc + lmb[u-45];
        }
    }
}

__global__ __launch_bounds__(256) void decode_kernel(
    const float* __restrict__ deltas, float* __restrict__ s_arr,
    float* __restrict__ boxes, float* __restrict__ anch_out,
    u64* __restrict__ slot)
{
    int n = blockIdx.x*256 + threadIdx.x;
    if (n < 8) slot[n] = 0ull;
    if (n >= NANCH) return;
    int p = n / 9, a = n - 9*p;
    int y = p / FW, x = p - FW*y;
    float cx = (x + 0.5f)*STRIDE, cy = (y + 0.5f)*STRIDE;
    const float rr[3] = {0.5f, 1.f, 2.f};
    const float ss[3] = {8.f, 16.f, 32.f};
    float r = rr[a/3], sv = ss[a - (a/3)*3];
    float h  = sqrtf(sv*sv/r)*STRIDE;
    float wv = h * r;
    float x1a = cx - wv*0.5f, y1a = cy - h*0.5f;
    float x2a = cx + wv*0.5f, y2a = cy + h*0.5f;
    float4 av = {x1a, y1a, x2a, y2a};
    *(float4*)(anch_out + (size_t)4*n) = av;
    bool valid = (x1a >= 0.f) && (y1a >= 0.f) && (x2a <= IMG) && (y2a <= IMG);

    float4 d = *(const float4*)(deltas + (size_t)4*n);
    float px = cx + wv*d.x, py = cy + h*d.y;
    float pw = wv*expf(d.z), ph = h*expf(d.w);
    float bx1 = px - pw*0.5f, by1 = py - ph*0.5f;
    float4 b;
    b.x = fminf(fmaxf(bx1, 0.f), IMG);
    b.y = fminf(fmaxf(by1, 0.f), IMG);
    b.z = fminf(fmaxf(bx1 + pw, 0.f), IMG);
    b.w = fminf(fmaxf(by1 + ph, 0.f), IMG);
    *(float4*)(boxes + (size_t)4*n) = b;
    if (!valid) s_arr[n] = -1.f;
}

__global__ __launch_bounds__(256) void nms_iter_kernel(
    const float* __restrict__ boxes, float* __restrict__ s_arr,
    u64* __restrict__ slot, int k)
{
    __shared__ u64 red[4];
    int n = blockIdx.x*256 + threadIdx.x;
    float s = s_arr[n];
    if (k > 0) {
        unsigned int wn = ~(unsigned int)(slot[k-1] & 0xFFFFFFFFull);
        float4 wb = *(const float4*)(boxes + (size_t)4*wn);
        float4 b  = *(const float4*)(boxes + (size_t)4*n);
        float ix = fminf(wb.z, b.z) - fmaxf(wb.x, b.x);
        float iy = fminf(wb.w, b.w) - fmaxf(wb.y, b.y);
        float inter = fmaxf(ix, 0.f)*fmaxf(iy, 0.f);
        float a1 = (wb.z-wb.x)*(wb.w-wb.y);
        float a2 = (b.z-b.x)*(b.w-b.y);
        float iou = inter/(a1 + a2 - inter + 1e-9f);
        if (iou > 0.5f) { s = -1.f; s_arr[n] = -1.f; }
    }
    u64 packed = pack_key(s, n);
    packed = wave_max64(packed);
    if ((threadIdx.x & 63) == 0) red[threadIdx.x >> 6] = packed;
    __syncthreads();
    if (threadIdx.x == 0) {
        u64 m = red[0];
        m = m > red[1] ? m : red[1];
        m = m > red[2] ? m : red[2];
        m = m > red[3] ? m : red[3];
        atomicMax(&slot[k], m);
    }
}

__global__ void nms_fin_kernel(
    const float* __restrict__ boxes,
    const u64* __restrict__ slot, float* __restrict__ rois)
{
    int t = threadIdx.x;
    if (t < 6) {
        unsigned int n = ~(unsigned int)(slot[t] & 0xFFFFFFFFull);
        float4 b = *(const float4*)(boxes + (size_t)4*n);
        *(float4*)(rois + 4*t) = b;
    }
}

// ---------------------------------------------------------------------------
extern "C" void kernel_launch(void* const* d_in, const int* in_sizes, int n_in,
                              void* d_out, int out_size, void* d_ws, size_t ws_size,
                              hipStream_t stream)
{
    const float* f    = (const float*)d_in[0];
    const float* c1w  = (const float*)d_in[2];
    const float* c1b  = (const float*)d_in[3];
    const float* regw = (const float*)d_in[4];
    const float* regb = (const float*)d_in[5];
    const float* clsw = (const float*)d_in[6];
    const float* clsb = (const float*)d_in[7];
    const float* lmw  = (const float*)d_in[8];
    const float* lmb  = (const float*)d_in[9];

    float* out      = (float*)d_out;
    float* rois     = out;
    float* lm_out   = out + 24;
    float* anch_out = out + 24 + (size_t)NPOS*54;

    char* ws = (char*)d_ws;

    if (ws_size >= 62550016ull) {
        u64* blockmax = (u64*)ws;                                 //      3,200
        unsigned* cnt = (unsigned*)(ws + 3584);                   //          4
        unsigned short* wh  = (unsigned short*)(ws + 4096);       //    131,072
        unsigned short* fph = (unsigned short*)(ws + 135168);     // 26,873,856
        unsigned short* wt  = (unsigned short*)(ws + 27009024);   //  4,718,592
        unsigned short* xh  = (unsigned short*)(ws + 31727616);   // 26,214,400
        float* boxes  = (float*)(ws + 57942016);                  //  3,686,400
        float* s_arr  = (float*)(ws + 61628416);                  //    921,600

        prep_kernel<<<15682, 256, 0, stream>>>(f, c1w, regw, clsw, lmw,
                                               fph, wt, wh, cnt);
        conv1_mfma_kernel<<<800, 256, 0, stream>>>(fph, wt, c1b, xh);
        heads_mfma_kernel<<<NBLK, 256, 0, stream>>>(xh, wh, regb, clsb, lmb,
                                                    lm_out, boxes, anch_out,
                                                    s_arr, blockmax, cnt, rois);
    } else {
        u64* slot = (u64*)ws;
        float* wT     = (float*)(ws + 256);
        float* boxes  = (float*)(ws + 256 + 202752);
        float* deltas = (float*)(ws + 256 + 202752 + 3686400);
        float* s_arr  = (float*)(ws + 256 + 202752 + 2*3686400);
        float* x      = (float*)(ws + 256 + 202752 + 2*3686400 + 921600);

        wprep_kernel<<<(99*512 + 255)/256, 256, 0, stream>>>(regw, clsw, lmw, wT);
        conv1_kernel<<<dim3(8, 400), 256, 0, stream>>>(f, c1w, c1b, x);
        heads_kernel<<<NPOS/16, 256, 0, stream>>>(x, wT, regb, clsb, lmb,
                                                  lm_out, deltas, s_arr);
        decode_kernel<<<NANCH/256, 256, 0, stream>>>(deltas, s_arr, boxes,
                                                     anch_out, slot);
        for (int k = 0; k < 6; ++k)
            nms_iter_kernel<<<NANCH/256, 256, 0, stream>>>(boxes, s_arr, slot, k);
        nms_fin_kernel<<<1, 64, 0, stream>>>(boxes, slot, rois);
    }
}

// Round 8
// 390.781 us; speedup vs baseline: 1.6575x; 1.6575x over previous
//
#include <hip/hip_runtime.h>
#include <math.h>

#define FH 160
#define FW 160
#define NPOS (FH*FW)        // 25600
#define NANCH (NPOS*9)      // 230400
#define IMG 2560.0f
#define STRIDE 16.0f
#define PREP_VBLK 15682     // virtual prep blocks (work items / 256)
#define PREP_GRID 1024      // real prep grid (dispatch-rate bound fix)

typedef __attribute__((ext_vector_type(8))) _Float16 half8;
typedef __attribute__((ext_vector_type(4))) float f32x4;
typedef unsigned long long u64;

__device__ __forceinline__ unsigned short f2h(float v) {
    _Float16 h = (_Float16)v;          // RNE
    return *(unsigned short*)&h;
}
__device__ __forceinline__ void g2l16(void* lds, const void* g) {
    __builtin_amdgcn_global_load_lds(
        (const __attribute__((address_space(1))) void*)g,
        (__attribute__((address_space(3))) void*)lds, 16, 0, 0);
}
__device__ __forceinline__ u64 pack_key(float s, int n) {
    unsigned int bu = __float_as_uint(s);
    unsigned int key = (bu & 0x80000000u) ? ~bu : (bu | 0x80000000u);
    return ((u64)key << 32) | (unsigned int)~(unsigned int)n;
}
__device__ __forceinline__ u64 wave_max64(u64 v) {
#pragma unroll
    for (int off = 32; off > 0; off >>= 1) {
        u64 o = __shfl_xor(v, off, 64);
        v = v > o ? v : o;
    }
    return v;
}

// ---------------------------------------------------------------------------
// prep: fused feature pad+fp16 / conv1-W transpose+fp16 / head-W pack.
// GRID-STRIDED over 15682 virtual blocks from only 1024 real blocks:
// R7 isolated prep at ~155 us vs ~30 us roofline — 15682 trivial workgroup
// dispatches are CP-dispatch-rate bound (~100 WG/us). Same per-item work.
// ---------------------------------------------------------------------------
__global__ __launch_bounds__(256) void prep_kernel(
    const float* __restrict__ f, const float* __restrict__ w,
    const float* __restrict__ regw, const float* __restrict__ clsw,
    const float* __restrict__ lmw,
    unsigned short* __restrict__ fph, unsigned short* __restrict__ wt,
    unsigned short* __restrict__ wh)
{
    __shared__ float tile[32][33];
    const int t = threadIdx.x;
    for (int bid = blockIdx.x; bid < PREP_VBLK; bid += PREP_GRID) {
        if (bid < 13122) {                  // features: 162*162*128 items
            int idx = bid*256 + t;
            int c4 = (idx & 127) << 2;
            int rest = idx >> 7;
            int x = rest % 162, y = rest / 162;
            float4 v = make_float4(0.f, 0.f, 0.f, 0.f);
            if (y > 0 && y < 161 && x > 0 && x < 161)
                v = *(const float4*)(f + ((size_t)((y-1)*FW + (x-1)) << 9) + c4);
            ushort4 h;
            h.x = f2h(v.x); h.y = f2h(v.y); h.z = f2h(v.z); h.w = f2h(v.w);
            *(ushort4*)(fph + ((size_t)(y*162 + x) << 9) + c4) = h;
        } else if (bid < 15426) {           // conv1 W: 144 x 16 transpose tiles
            int b = bid - 13122;
            int k0 = (b % 144)*32, oc0 = (b / 144)*32;
            int c = t & 31, r8 = t >> 5;
#pragma unroll
            for (int i = 0; i < 4; ++i) {
                int r = r8 + i*8;
                tile[c][r] = w[(size_t)(k0 + r)*512 + oc0 + c];
            }
            __syncthreads();
#pragma unroll
            for (int i = 0; i < 4; ++i) {
                int orow = r8 + i*8, kcol = c;
                wt[(size_t)(oc0 + orow)*4608 + k0 + kcol] = f2h(tile[orow][kcol]);
            }
            __syncthreads();                // WAR guard: tile reused next vbid
        } else {                            // head W pack: 128x512
            int i = (bid - 15426)*256 + t;
            int u = i >> 9, c = i & 511;
            float v = 0.f;
            if (u < 36)      v = regw[c*72 + (u>>2)*8 + (u&3)];
            else if (u < 45) v = clsw[c*9 + (u-36)];
            else if (u < 99) v = lmw[c*54 + (u-45)];
            wh[i] = f2h(v);
        }
    }
}

// ---------------------------------------------------------------------------
// conv1 MFMA fp16, BM=BN=128 BK=64, 256 thr (2x2 waves), wave tile 64x64.
// FROZEN since R5: 178 us = 35% of f16 ceiling = the documented m97-structure
// plateau (control rows for the bench).
// ---------------------------------------------------------------------------
__global__ __launch_bounds__(256) void conv1_mfma_kernel(
    const unsigned short* __restrict__ fph, const unsigned short* __restrict__ wt,
    const float* __restrict__ bias, unsigned short* __restrict__ xh)
{
    __shared__ unsigned short As[128*64];
    __shared__ unsigned short Bs[128*64];
    const int tid  = threadIdx.x;
    const int lane = tid & 63;
    const int wi   = (tid >> 7) & 1;
    const int wj   = (tid >> 6) & 1;
    const int bid  = blockIdx.x;
    const int xcd  = bid & 7, sl = bid >> 3;
    const int oc0  = (xcd & 3) * 128;
    const int pt   = (xcd >> 2) * 100 + sl;
    const int ty = pt / 5, tx = pt - ty*5;
    const int y0 = ty*4, x0 = tx*32;

    const int srow = tid >> 3;               // 0..31
    const int kswz = (((tid & 7) ^ (srow & 7)) << 3);
    const int quad = lane >> 4, fr = lane & 15;

    f32x4 acc[4][4] = {};
    const size_t bBase = (size_t)(oc0 + srow)*4608 + kswz;

    for (int tap = 0; tap < 9; ++tap) {
        const int ky = tap/3, kx = tap - (tap/3)*3;
        const size_t aBase = ((size_t)((y0 + ky)*162 + (x0 + srow + kx)) << 9) + kswz;
        const size_t bTap  = bBase + tap*512;
        for (int icb = 0; icb < 512; icb += 64) {
#pragma unroll
            for (int r = 0; r < 4; ++r) {
                g2l16(As + tid*8 + r*2048, fph + aBase + (size_t)r*162*512 + icb);
                g2l16(Bs + tid*8 + r*2048, wt  + bTap  + (size_t)r*32*4608 + icb);
            }
            __syncthreads();
#pragma unroll
            for (int kk = 0; kk < 2; ++kk) {
                const int sa = ((kk*4 + quad) ^ (fr & 7)) << 3;
                half8 a[4], b[4];
#pragma unroll
                for (int i = 0; i < 4; ++i) {
                    a[i] = *(const half8*)(As + (wi*64 + i*16 + fr)*64 + sa);
                    b[i] = *(const half8*)(Bs + (wj*64 + i*16 + fr)*64 + sa);
                }
#pragma unroll
                for (int i = 0; i < 4; ++i)
#pragma unroll
                    for (int j = 0; j < 4; ++j)
                        acc[i][j] = __builtin_amdgcn_mfma_f32_16x16x32_f16(a[i], b[j], acc[i][j], 0, 0, 0);
            }
            __syncthreads();
        }
    }

#pragma unroll
    for (int i = 0; i < 4; ++i) {
#pragma unroll
        for (int r = 0; r < 4; ++r) {
            int mi = wi*64 + i*16 + quad*4 + r;
            int p = (y0 + (mi >> 5))*FW + x0 + (mi & 31);
#pragma unroll
            for (int j = 0; j < 4; ++j) {
                int col = oc0 + wj*64 + j*16 + fr;
                float v = acc[i][j][r] + bias[col];
                xh[(size_t)p*512 + col] = f2h(v > 0.f ? v : 0.f);
            }
        }
    }
}

// ---------------------------------------------------------------------------
// heads MFMA fp16 + fused decode/anchors + per-block NMS seed max.
// R6 structure (measured good). LDS union overlays epilogue onto staging
// (32.8KB -> 4 blocks/CU). Block b covers anchors [1152b, 1152(b+1)).
// ---------------------------------------------------------------------------
__global__ __launch_bounds__(256) void heads_mfma_kernel(
    const unsigned short* __restrict__ xh, const unsigned short* __restrict__ wh,
    const float* __restrict__ regb, const float* __restrict__ clsb,
    const float* __restrict__ lmb,
    float* __restrict__ lm_out, float* __restrict__ boxes,
    float* __restrict__ anch_out, float* __restrict__ s_arr,
    u64* __restrict__ blockmax)
{
    __shared__ union SM {
        struct { unsigned short As[128*64]; unsigned short Bs[128*64]; } g;
        struct { float sdel[128][40]; float scls[128][12]; u64 red[8]; } e;
    } sm;
    unsigned short* As = sm.g.As;
    unsigned short* Bs = sm.g.Bs;
    const int tid  = threadIdx.x;
    const int lane = tid & 63;
    const int wi   = (tid >> 7) & 1;
    const int wj   = (tid >> 6) & 1;
    const int p0   = blockIdx.x * 128;

    const int srow = tid >> 3;
    const int kswz = (((tid & 7) ^ (srow & 7)) << 3);
    const int quad = lane >> 4, fr = lane & 15;
    f32x4 acc[4][4] = {};

    const size_t aOfs = ((size_t)(p0 + srow) << 9) + kswz;
    const size_t bOfs = ((size_t)srow << 9) + kswz;

    for (int icb = 0; icb < 512; icb += 64) {
#pragma unroll
        for (int r = 0; r < 4; ++r) {
            g2l16(As + tid*8 + r*2048, xh + aOfs + (size_t)r*32*512 + icb);
            g2l16(Bs + tid*8 + r*2048, wh + bOfs + (size_t)r*32*512 + icb);
        }
        __syncthreads();
#pragma unroll
        for (int kk = 0; kk < 2; ++kk) {
            const int sa = ((kk*4 + quad) ^ (fr & 7)) << 3;
            half8 a[4], b[4];
#pragma unroll
            for (int i = 0; i < 4; ++i) {
                a[i] = *(const half8*)(As + (wi*64 + i*16 + fr)*64 + sa);
                b[i] = *(const half8*)(Bs + (wj*64 + i*16 + fr)*64 + sa);
            }
#pragma unroll
            for (int i = 0; i < 4; ++i)
#pragma unroll
                for (int j = 0; j < 4; ++j)
                    acc[i][j] = __builtin_amdgcn_mfma_f32_16x16x32_f16(a[i], b[j], acc[i][j], 0, 0, 0);
        }
        __syncthreads();
    }
    // K-loop done; LDS drained -> overlay epilogue structs.

#pragma unroll
    for (int i = 0; i < 4; ++i) {
#pragma unroll
        for (int r = 0; r < 4; ++r) {
            int pl = wi*64 + i*16 + quad*4 + r;
            int p = p0 + pl;
#pragma unroll
            for (int j = 0; j < 4; ++j) {
                int u = wj*64 + j*16 + fr;
                float v = acc[i][j][r];
                if (u < 36) {
                    sm.e.sdel[pl][u] = v + regb[(u>>2)*8 + (u&3)];
                } else if (u < 45) {
                    float z = v + clsb[u-36];
                    sm.e.scls[pl][u-36] = 1.f/(1.f + expf(-z));
                } else if (u < 99) {
                    lm_out[(size_t)p*54 + (u-45)] = v + lmb[u-45];
                }
            }
        }
    }
    __syncthreads();

    u64 local = 0ull;
    for (int t = tid; t < 128*9; t += 256) {
        int pl = t / 9, a = t - pl*9;
        int p = p0 + pl;
        int y = p / FW, x = p - FW*y;
        float cx = (x + 0.5f)*STRIDE, cy = (y + 0.5f)*STRIDE;
        const float rr[3] = {0.5f, 1.f, 2.f};
        const float ss[3] = {8.f, 16.f, 32.f};
        float r = rr[a/3], sv = ss[a - (a/3)*3];
        float h  = sqrtf(sv*sv/r)*STRIDE;
        float wvv = h * r;
        float x1a = cx - wvv*0.5f, y1a = cy - h*0.5f;
        float x2a = cx + wvv*0.5f, y2a = cy + h*0.5f;
        size_t n = (size_t)p*9 + a;
        float4 av = {x1a, y1a, x2a, y2a};
        *(float4*)(anch_out + 4*n) = av;
        bool valid = (x1a >= 0.f) && (y1a >= 0.f) && (x2a <= IMG) && (y2a <= IMG);

        float dx = sm.e.sdel[pl][a*4+0], dy = sm.e.sdel[pl][a*4+1];
        float dw = sm.e.sdel[pl][a*4+2], dh = sm.e.sdel[pl][a*4+3];
        float px = cx + wvv*dx, py = cy + h*dy;
        float pw = wvv*expf(dw), ph = h*expf(dh);
        float bx1 = px - pw*0.5f, by1 = py - ph*0.5f;
        float4 b;
        b.x = fminf(fmaxf(bx1, 0.f), IMG);
        b.y = fminf(fmaxf(by1, 0.f), IMG);
        b.z = fminf(fmaxf(bx1 + pw, 0.f), IMG);
        b.w = fminf(fmaxf(by1 + ph, 0.f), IMG);
        *(float4*)(boxes + 4*n) = b;
        float s = valid ? sm.e.scls[pl][a] : -1.f;
        s_arr[n] = s;
        u64 pk = pack_key(s, (int)n);
        local = local > pk ? local : pk;
    }
    local = wave_max64(local);
    if ((tid & 63) == 0) sm.e.red[tid >> 6] = local;
    __syncthreads();
    if (tid == 0) {
        u64 m = sm.e.red[0];
        m = m > sm.e.red[1] ? m : sm.e.red[1];
        m = m > sm.e.red[2] ? m : sm.e.red[2];
        m = m > sm.e.red[3] ? m : sm.e.red[3];
        blockmax[blockIdx.x] = m;
    }
}

// ---------------------------------------------------------------------------
// NMS round k (k=1..5), zero atomics (R6 structure): every block redundantly
// reduces blockmax[0..199] -> winner of round k-1 (block 0 writes rois[k-1]),
// suppresses its own 1152 anchors, recomputes blockmax[b].
// ---------------------------------------------------------------------------
__global__ __launch_bounds__(256) void nms_supp_kernel(
    const float* __restrict__ boxes, float* __restrict__ s_arr,
    u64* __restrict__ blockmax, float* __restrict__ rois, int k)
{
    __shared__ u64 red[4];
    __shared__ u64 win_sh;
    const int tid = threadIdx.x;

    u64 v = (tid < 200) ? blockmax[tid] : 0ull;
    v = wave_max64(v);
    if ((tid & 63) == 0) red[tid >> 6] = v;
    __syncthreads();
    if (tid == 0) {
        u64 m = red[0];
        m = m > red[1] ? m : red[1];
        m = m > red[2] ? m : red[2];
        m = m > red[3] ? m : red[3];
        win_sh = m;
    }
    __syncthreads();
    const unsigned int wn = ~(unsigned int)(win_sh & 0xFFFFFFFFull);
    const float4 wb = *(const float4*)(boxes + (size_t)4*wn);
    if (blockIdx.x == 0 && tid == 0)
        *(float4*)(rois + 4*(k-1)) = wb;

    const float wa = (wb.z - wb.x)*(wb.w - wb.y);
    const int base = blockIdx.x * 1152;
    u64 local = 0ull;
    for (int i = tid; i < 1152; i += 256) {
        int n = base + i;
        float s = s_arr[n];
        float4 b = *(const float4*)(boxes + (size_t)4*n);
        float ix = fminf(wb.z, b.z) - fmaxf(wb.x, b.x);
        float iy = fminf(wb.w, b.w) - fmaxf(wb.y, b.y);
        float inter = fmaxf(ix, 0.f)*fmaxf(iy, 0.f);
        float a2 = (b.z - b.x)*(b.w - b.y);
        float iou = inter/(wa + a2 - inter + 1e-9f);
        if (iou > 0.5f && s > -1.f) { s = -1.f; s_arr[n] = -1.f; }
        u64 pk = pack_key(s, n);
        local = local > pk ? local : pk;
    }
    local = wave_max64(local);
    if ((tid & 63) == 0) red[tid >> 6] = local;
    __syncthreads();
    if (tid == 0) {
        u64 m = red[0];
        m = m > red[1] ? m : red[1];
        m = m > red[2] ? m : red[2];
        m = m > red[3] ? m : red[3];
        blockmax[blockIdx.x] = m;
    }
}

__global__ void nms_fin2_kernel(
    const float* __restrict__ boxes, const u64* __restrict__ blockmax,
    float* __restrict__ rois)
{
    __shared__ u64 red[4];
    const int tid = threadIdx.x;   // 256
    u64 v = (tid < 200) ? blockmax[tid] : 0ull;
    v = wave_max64(v);
    if ((tid & 63) == 0) red[tid >> 6] = v;
    __syncthreads();
    if (tid == 0) {
        u64 m = red[0];
        m = m > red[1] ? m : red[1];
        m = m > red[2] ? m : red[2];
        m = m > red[3] ? m : red[3];
        unsigned int wn = ~(unsigned int)(m & 0xFFFFFFFFull);
        *(float4*)(rois + 20) = *(const float4*)(boxes + (size_t)4*wn);
    }
}

// ---------------------------------------------------------------------------
// fallback fp32 path kernels (known-good round-1 structure)
// ---------------------------------------------------------------------------
__global__ __launch_bounds__(256) void conv1_kernel(
    const float* __restrict__ f, const float* __restrict__ w,
    const float* __restrict__ bias, float* __restrict__ xout)
{
    __shared__ float As2[32][66];
    __shared__ float Bs2[32][66];
    const int tid = threadIdx.x;
    const int nt = blockIdx.x;
    const int mt = blockIdx.y;
    const int p0 = mt*64, oc0 = nt*64;
    const int tm = tid & 15, tn = tid >> 4;
    const int kA = tid & 31, mA = tid >> 5;
    const int nB = tid & 63, kB = tid >> 6;
    int yv[8], xv[8];
#pragma unroll
    for (int it = 0; it < 8; ++it) {
        int p = p0 + mA + it*8;
        yv[it] = p / FW;
        xv[it] = p - yv[it]*FW;
    }
    float acc[4][4] = {};
    for (int tap = 0; tap < 9; ++tap) {
        const int ky = tap/3 - 1, kx = tap%3 - 1;
        for (int icb = 0; icb < 512; icb += 32) {
#pragma unroll
            for (int it = 0; it < 8; ++it) {
                int yy = yv[it] + ky, xx = xv[it] + kx;
                float v = 0.f;
                if ((unsigned)yy < (unsigned)FH && (unsigned)xx < (unsigned)FW)
                    v = f[(((yy*FW)+xx)<<9) + icb + kA];
                As2[kA][mA + it*8] = v;
            }
            const float* wp = w + ((size_t)(tap*512 + icb + kB))*512 + oc0 + nB;
#pragma unroll
            for (int it = 0; it < 8; ++it)
                Bs2[kB + it*4][nB] = wp[(size_t)it*4*512];
            __syncthreads();
#pragma unroll 8
            for (int kk = 0; kk < 32; ++kk) {
                float a0 = As2[kk][4*tm+0], a1 = As2[kk][4*tm+1],
                      a2 = As2[kk][4*tm+2], a3 = As2[kk][4*tm+3];
                float b0 = Bs2[kk][4*tn+0], b1 = Bs2[kk][4*tn+1],
                      b2 = Bs2[kk][4*tn+2], b3 = Bs2[kk][4*tn+3];
                acc[0][0] += a0*b0; acc[0][1] += a0*b1; acc[0][2] += a0*b2; acc[0][3] += a0*b3;
                acc[1][0] += a1*b0; acc[1][1] += a1*b1; acc[1][2] += a1*b2; acc[1][3] += a1*b3;
                acc[2][0] += a2*b0; acc[2][1] += a2*b1; acc[2][2] += a2*b2; acc[2][3] += a2*b3;
                acc[3][0] += a3*b0; acc[3][1] += a3*b1; acc[3][2] += a3*b2; acc[3][3] += a3*b3;
            }
            __syncthreads();
        }
    }
#pragma unroll
    for (int i = 0; i < 4; ++i) {
        int p = p0 + 4*tm + i;
        float4 o;
        float* op = &o.x;
#pragma unroll
        for (int j = 0; j < 4; ++j) {
            float v = acc[i][j] + bias[oc0 + 4*tn + j];
            op[j] = v > 0.f ? v : 0.f;
        }
        *(float4*)(xout + (size_t)p*512 + oc0 + 4*tn) = o;
    }
}

__global__ __launch_bounds__(256) void wprep_kernel(
    const float* __restrict__ regw, const float* __restrict__ clsw,
    const float* __restrict__ lmw, float* __restrict__ wT)
{
    int i = blockIdx.x*256 + threadIdx.x;
    if (i >= 99*512) return;
    int u = i >> 9, c = i & 511;
    float v;
    if (u < 36)      v = regw[c*72 + (u>>2)*8 + (u&3)];
    else if (u < 45) v = clsw[c*9 + (u-36)];
    else             v = lmw[c*54 + (u-45)];
    wT[i] = v;
}

__global__ __launch_bounds__(256) void heads_kernel(
    const float* __restrict__ x, const float* __restrict__ wT,
    const float* __restrict__ regb, const float* __restrict__ clsb,
    const float* __restrict__ lmb,
    float* __restrict__ lm_out, float* __restrict__ deltas,
    float* __restrict__ s_arr)
{
    __shared__ float xs[16*516];
    const int p0 = blockIdx.x * 16;
    const float4* src = (const float4*)(x + (size_t)p0*512);
    for (int i = threadIdx.x; i < 16*128; i += 256) {
        int row = i >> 7, c4 = i & 127;
        *(float4*)(xs + row*516 + c4*4) = src[row*128 + c4];
    }
    __syncthreads();
    for (int oi = threadIdx.x; oi < 99*16; oi += 256) {
        int ps = oi & 15, u = oi >> 4;
        const float4* wv = (const float4*)(wT + (u << 9));
        const float4* xv = (const float4*)(xs + ps*516);
        float acc = 0.f;
#pragma unroll 4
        for (int c = 0; c < 128; ++c) {
            float4 a = xv[c], b = wv[c];
            acc += a.x*b.x + a.y*b.y + a.z*b.z + a.w*b.w;
        }
        int p = p0 + ps;
        if (u < 36) {
            int aidx = u >> 2, r = u & 3;
            deltas[(size_t)(p*9 + aidx)*4 + r] = acc + regb[aidx*8 + r];
        } else if (u < 45) {
            float z = acc + clsb[u-36];
            s_arr[p*9 + (u-36)] = 1.f/(1.f + expf(-z));
        } else {
            lm_out[(size_t)p*54 + (u-45)] = acc + lmb[u-45];
        }
    }
}

__global__ __launch_bounds__(256) void decode_kernel(
    const float* __restrict__ deltas, float* __restrict__ s_arr,
    float* __restrict__ boxes, float* __restrict__ anch_out,
    u64* __restrict__ slot)
{
    int n = blockIdx.x*256 + threadIdx.x;
    if (n < 8) slot[n] = 0ull;
    if (n >= NANCH) return;
    int p = n / 9, a = n - 9*p;
    int y = p / FW, x = p - FW*y;
    float cx = (x + 0.5f)*STRIDE, cy = (y + 0.5f)*STRIDE;
    const float rr[3] = {0.5f, 1.f, 2.f};
    const float ss[3] = {8.f, 16.f, 32.f};
    float r = rr[a/3], sv = ss[a - (a/3)*3];
    float h  = sqrtf(sv*sv/r)*STRIDE;
    float wv = h * r;
    float x1a = cx - wv*0.5f, y1a = cy - h*0.5f;
    float x2a = cx + wv*0.5f, y2a = cy + h*0.5f;
    float4 av = {x1a, y1a, x2a, y2a};
    *(float4*)(anch_out + (size_t)4*n) = av;
    bool valid = (x1a >= 0.f) && (y1a >= 0.f) && (x2a <= IMG) && (y2a <= IMG);

    float4 d = *(const float4*)(deltas + (size_t)4*n);
    float px = cx + wv*d.x, py = cy + h*d.y;
    float pw = wv*expf(d.z), ph = h*expf(d.w);
    float bx1 = px - pw*0.5f, by1 = py - ph*0.5f;
    float4 b;
    b.x = fminf(fmaxf(bx1, 0.f), IMG);
    b.y = fminf(fmaxf(by1, 0.f), IMG);
    b.z = fminf(fmaxf(bx1 + pw, 0.f), IMG);
    b.w = fminf(fmaxf(by1 + ph, 0.f), IMG);
    *(float4*)(boxes + (size_t)4*n) = b;
    if (!valid) s_arr[n] = -1.f;
}

__global__ __launch_bounds__(256) void nms_iter_kernel(
    const float* __restrict__ boxes, float* __restrict__ s_arr,
    u64* __restrict__ slot, int k)
{
    __shared__ u64 red[4];
    int n = blockIdx.x*256 + threadIdx.x;
    float s = s_arr[n];
    if (k > 0) {
        unsigned int wn = ~(unsigned int)(slot[k-1] & 0xFFFFFFFFull);
        float4 wb = *(const float4*)(boxes + (size_t)4*wn);
        float4 b  = *(const float4*)(boxes + (size_t)4*n);
        float ix = fminf(wb.z, b.z) - fmaxf(wb.x, b.x);
        float iy = fminf(wb.w, b.w) - fmaxf(wb.y, b.y);
        float inter = fmaxf(ix, 0.f)*fmaxf(iy, 0.f);
        float a1 = (wb.z-wb.x)*(wb.w-wb.y);
        float a2 = (b.z-b.x)*(b.w-b.y);
        float iou = inter/(a1 + a2 - inter + 1e-9f);
        if (iou > 0.5f) { s = -1.f; s_arr[n] = -1.f; }
    }
    u64 packed = pack_key(s, n);
    packed = wave_max64(packed);
    if ((threadIdx.x & 63) == 0) red[threadIdx.x >> 6] = packed;
    __syncthreads();
    if (threadIdx.x == 0) {
        u64 m = red[0];
        m = m > red[1] ? m : red[1];
        m = m > red[2] ? m : red[2];
        m = m > red[3] ? m : red[3];
        atomicMax(&slot[k], m);
    }
}

__global__ void nms_fin_kernel(
    const float* __restrict__ boxes,
    const u64* __restrict__ slot, float* __restrict__ rois)
{
    int t = threadIdx.x;
    if (t < 6) {
        unsigned int n = ~(unsigned int)(slot[t] & 0xFFFFFFFFull);
        float4 b = *(const float4*)(boxes + (size_t)4*n);
        *(float4*)(rois + 4*t) = b;
    }
}

// ---------------------------------------------------------------------------
extern "C" void kernel_launch(void* const* d_in, const int* in_sizes, int n_in,
                              void* d_out, int out_size, void* d_ws, size_t ws_size,
                              hipStream_t stream)
{
    const float* f    = (const float*)d_in[0];
    const float* c1w  = (const float*)d_in[2];
    const float* c1b  = (const float*)d_in[3];
    const float* regw = (const float*)d_in[4];
    const float* regb = (const float*)d_in[5];
    const float* clsw = (const float*)d_in[6];
    const float* clsb = (const float*)d_in[7];
    const float* lmw  = (const float*)d_in[8];
    const float* lmb  = (const float*)d_in[9];

    float* out      = (float*)d_out;
    float* rois     = out;
    float* lm_out   = out + 24;
    float* anch_out = out + 24 + (size_t)NPOS*54;

    char* ws = (char*)d_ws;

    if (ws_size >= 62547968ull) {
        u64* blockmax = (u64*)ws;                                 //      1,600
        unsigned short* wh  = (unsigned short*)(ws + 2048);       //    131,072
        unsigned short* fph = (unsigned short*)(ws + 133120);     // 26,873,856
        unsigned short* wt  = (unsigned short*)(ws + 27006976);   //  4,718,592
        unsigned short* xh  = (unsigned short*)(ws + 31725568);   // 26,214,400
        float* boxes  = (float*)(ws + 57939968);                  //  3,686,400
        float* s_arr  = (float*)(ws + 61626368);                  //    921,600

        prep_kernel<<<PREP_GRID, 256, 0, stream>>>(f, c1w, regw, clsw, lmw,
                                                   fph, wt, wh);
        conv1_mfma_kernel<<<800, 256, 0, stream>>>(fph, wt, c1b, xh);
        heads_mfma_kernel<<<200, 256, 0, stream>>>(xh, wh, regb, clsb, lmb,
                                                   lm_out, boxes, anch_out,
                                                   s_arr, blockmax);
        for (int k = 1; k <= 5; ++k)
            nms_supp_kernel<<<200, 256, 0, stream>>>(boxes, s_arr, blockmax,
                                                     rois, k);
        nms_fin2_kernel<<<1, 256, 0, stream>>>(boxes, blockmax, rois);
    } else {
        u64* slot = (u64*)ws;
        float* wT     = (float*)(ws + 256);
        float* boxes  = (float*)(ws + 256 + 202752);
        float* deltas = (float*)(ws + 256 + 202752 + 3686400);
        float* s_arr  = (float*)(ws + 256 + 202752 + 2*3686400);
        float* x      = (float*)(ws + 256 + 202752 + 2*3686400 + 921600);

        wprep_kernel<<<(99*512 + 255)/256, 256, 0, stream>>>(regw, clsw, lmw, wT);
        conv1_kernel<<<dim3(8, 400), 256, 0, stream>>>(f, c1w, c1b, x);
        heads_kernel<<<NPOS/16, 256, 0, stream>>>(x, wT, regb, clsb, lmb,
                                                  lm_out, deltas, s_arr);
        decode_kernel<<<NANCH/256, 256, 0, stream>>>(deltas, s_arr, boxes,
                                                     anch_out, slot);
        for (int k = 0; k < 6; ++k)
            nms_iter_kernel<<<NANCH/256, 256, 0, stream>>>(boxes, s_arr, slot, k);
        nms_fin_kernel<<<1, 64, 0, stream>>>(boxes, slot, rois);
    }
}

// Round 9
// 389.110 us; speedup vs baseline: 1.6646x; 1.0043x over previous
//
#include <hip/hip_runtime.h>
#include <math.h>

#define FH 160
#define FW 160
#define NPOS (FH*FW)        // 25600
#define NANCH (NPOS*9)      // 230400
#define IMG 2560.0f
#define STRIDE 16.0f
#define PREP_VBLK 15682
#define PREP_GRID 1024
#define HB 400              // heads grid (BM=64)
#define HANCH 576           // anchors per heads block

typedef __attribute__((ext_vector_type(8))) _Float16 half8;
typedef __attribute__((ext_vector_type(4))) float f32x4;
typedef unsigned long long u64;

__device__ __forceinline__ unsigned short f2h(float v) {
    _Float16 h = (_Float16)v;          // RNE
    return *(unsigned short*)&h;
}
__device__ __forceinline__ void g2l16(void* lds, const void* g) {
    __builtin_amdgcn_global_load_lds(
        (const __attribute__((address_space(1))) void*)g,
        (__attribute__((address_space(3))) void*)lds, 16, 0, 0);
}
__device__ __forceinline__ u64 pack_key(float s, int n) {
    unsigned int bu = __float_as_uint(s);
    unsigned int key = (bu & 0x80000000u) ? ~bu : (bu | 0x80000000u);
    return ((u64)key << 32) | (unsigned int)~(unsigned int)n;
}
__device__ __forceinline__ u64 wave_max64(u64 v) {
#pragma unroll
    for (int off = 32; off > 0; off >>= 1) {
        u64 o = __shfl_xor(v, off, 64);
        v = v > o ? v : o;
    }
    return v;
}

// ---------------------------------------------------------------------------
// prep: fused feature pad+fp16 / conv1-W transpose+fp16 / head-W pack.
// Grid-strided (R8: dispatch-count neutral, kept for fewer WG dispatches).
// ---------------------------------------------------------------------------
__global__ __launch_bounds__(256) void prep_kernel(
    const float* __restrict__ f, const float* __restrict__ w,
    const float* __restrict__ regw, const float* __restrict__ clsw,
    const float* __restrict__ lmw,
    unsigned short* __restrict__ fph, unsigned short* __restrict__ wt,
    unsigned short* __restrict__ wh)
{
    __shared__ float tile[32][33];
    const int t = threadIdx.x;
    for (int bid = blockIdx.x; bid < PREP_VBLK; bid += PREP_GRID) {
        if (bid < 13122) {                  // features: 162*162*128 items
            int idx = bid*256 + t;
            int c4 = (idx & 127) << 2;
            int rest = idx >> 7;
            int x = rest % 162, y = rest / 162;
            float4 v = make_float4(0.f, 0.f, 0.f, 0.f);
            if (y > 0 && y < 161 && x > 0 && x < 161)
                v = *(const float4*)(f + ((size_t)((y-1)*FW + (x-1)) << 9) + c4);
            ushort4 h;
            h.x = f2h(v.x); h.y = f2h(v.y); h.z = f2h(v.z); h.w = f2h(v.w);
            *(ushort4*)(fph + ((size_t)(y*162 + x) << 9) + c4) = h;
        } else if (bid < 15426) {           // conv1 W: 144 x 16 transpose tiles
            int b = bid - 13122;
            int k0 = (b % 144)*32, oc0 = (b / 144)*32;
            int c = t & 31, r8 = t >> 5;
#pragma unroll
            for (int i = 0; i < 4; ++i) {
                int r = r8 + i*8;
                tile[c][r] = w[(size_t)(k0 + r)*512 + oc0 + c];
            }
            __syncthreads();
#pragma unroll
            for (int i = 0; i < 4; ++i) {
                int orow = r8 + i*8, kcol = c;
                wt[(size_t)(oc0 + orow)*4608 + k0 + kcol] = f2h(tile[orow][kcol]);
            }
            __syncthreads();                // WAR guard: tile reused next vbid
        } else {                            // head W pack: 128x512
            int i = (bid - 15426)*256 + t;
            int u = i >> 9, c = i & 511;
            float v = 0.f;
            if (u < 36)      v = regw[c*72 + (u>>2)*8 + (u&3)];
            else if (u < 45) v = clsw[c*9 + (u-36)];
            else if (u < 99) v = lmw[c*54 + (u-45)];
            wh[i] = f2h(v);
        }
    }
}

// ---------------------------------------------------------------------------
// conv1 MFMA fp16, BM=BN=128 BK=64, 256 thr (2x2 waves), wave tile 64x64.
// R9 change: block order pt-major with the 4 oc-tiles CONSECUTIVE (temporal
// L2 locality for the shared A-tile) instead of the bid&7 "XCD swizzle" —
// block->XCD mapping is undefined (guide G16), and FETCH=454MB vs 36MB unique
// working set says the old order scattered locality.
// ---------------------------------------------------------------------------
__global__ __launch_bounds__(256) void conv1_mfma_kernel(
    const unsigned short* __restrict__ fph, const unsigned short* __restrict__ wt,
    const float* __restrict__ bias, unsigned short* __restrict__ xh)
{
    __shared__ unsigned short As[128*64];
    __shared__ unsigned short Bs[128*64];
    const int tid  = threadIdx.x;
    const int lane = tid & 63;
    const int wi   = (tid >> 7) & 1;
    const int wj   = (tid >> 6) & 1;
    const int bid  = blockIdx.x;
    const int pt   = bid >> 2;           // 0..199, raster over pos tiles
    const int oc0  = (bid & 3) * 128;    // 4 oc-tiles adjacent in dispatch
    const int ty = pt / 5, tx = pt - ty*5;
    const int y0 = ty*4, x0 = tx*32;

    const int srow = tid >> 3;               // 0..31
    const int kswz = (((tid & 7) ^ (srow & 7)) << 3);
    const int quad = lane >> 4, fr = lane & 15;

    f32x4 acc[4][4] = {};
    const size_t bBase = (size_t)(oc0 + srow)*4608 + kswz;

    for (int tap = 0; tap < 9; ++tap) {
        const int ky = tap/3, kx = tap - (tap/3)*3;
        const size_t aBase = ((size_t)((y0 + ky)*162 + (x0 + srow + kx)) << 9) + kswz;
        const size_t bTap  = bBase + tap*512;
        for (int icb = 0; icb < 512; icb += 64) {
#pragma unroll
            for (int r = 0; r < 4; ++r) {
                g2l16(As + tid*8 + r*2048, fph + aBase + (size_t)r*162*512 + icb);
                g2l16(Bs + tid*8 + r*2048, wt  + bTap  + (size_t)r*32*4608 + icb);
            }
            __syncthreads();
#pragma unroll
            for (int kk = 0; kk < 2; ++kk) {
                const int sa = ((kk*4 + quad) ^ (fr & 7)) << 3;
                half8 a[4], b[4];
#pragma unroll
                for (int i = 0; i < 4; ++i) {
                    a[i] = *(const half8*)(As + (wi*64 + i*16 + fr)*64 + sa);
                    b[i] = *(const half8*)(Bs + (wj*64 + i*16 + fr)*64 + sa);
                }
#pragma unroll
                for (int i = 0; i < 4; ++i)
#pragma unroll
                    for (int j = 0; j < 4; ++j)
                        acc[i][j] = __builtin_amdgcn_mfma_f32_16x16x32_f16(a[i], b[j], acc[i][j], 0, 0, 0);
            }
            __syncthreads();
        }
    }

#pragma unroll
    for (int i = 0; i < 4; ++i) {
#pragma unroll
        for (int r = 0; r < 4; ++r) {
            int mi = wi*64 + i*16 + quad*4 + r;
            int p = (y0 + (mi >> 5))*FW + x0 + (mi & 31);
#pragma unroll
            for (int j = 0; j < 4; ++j) {
                int col = oc0 + wj*64 + j*16 + fr;
                float v = acc[i][j][r] + bias[col];
                xh[(size_t)p*512 + col] = f2h(v > 0.f ? v : 0.f);
            }
        }
    }
}

// ---------------------------------------------------------------------------
// heads MFMA fp16, BM=64 -> 400 blocks (latency hiding; R7-verified GEMM)
// + fused decode/anchors + per-block NMS seed max. LDS 24.6KB.
// ---------------------------------------------------------------------------
__global__ __launch_bounds__(256) void heads_mfma_kernel(
    const unsigned short* __restrict__ xh, const unsigned short* __restrict__ wh,
    const float* __restrict__ regb, const float* __restrict__ clsb,
    const float* __restrict__ lmb,
    float* __restrict__ lm_out, float* __restrict__ boxes,
    float* __restrict__ anch_out, float* __restrict__ s_arr,
    u64* __restrict__ blockmax)
{
    __shared__ union SM {
        struct { unsigned short As[64*64]; unsigned short Bs[128*64]; } g;
        struct { float sdel[64][40]; float scls[64][12]; u64 red[4]; } e;
    } sm;
    unsigned short* As = sm.g.As;
    unsigned short* Bs = sm.g.Bs;
    const int tid  = threadIdx.x;
    const int lane = tid & 63;
    const int wi   = (tid >> 7) & 1;     // m-half (32 rows)
    const int wj   = (tid >> 6) & 1;     // n-half (64 cols)
    const int p0   = blockIdx.x * 64;

    const int srow = tid >> 3;           // 0..31
    const int kswz = (((tid & 7) ^ (srow & 7)) << 3);
    const int quad = lane >> 4, fr = lane & 15;
    f32x4 acc[2][4] = {};

    const size_t aOfs = ((size_t)(p0 + srow) << 9) + kswz;
    const size_t bOfs = ((size_t)srow << 9) + kswz;

    for (int icb = 0; icb < 512; icb += 64) {
#pragma unroll
        for (int r = 0; r < 2; ++r)
            g2l16(As + tid*8 + r*2048, xh + aOfs + (size_t)r*32*512 + icb);
#pragma unroll
        for (int r = 0; r < 4; ++r)
            g2l16(Bs + tid*8 + r*2048, wh + bOfs + (size_t)r*32*512 + icb);
        __syncthreads();
#pragma unroll
        for (int kk = 0; kk < 2; ++kk) {
            const int sa = ((kk*4 + quad) ^ (fr & 7)) << 3;
            half8 a[2], b[4];
#pragma unroll
            for (int i = 0; i < 2; ++i)
                a[i] = *(const half8*)(As + (wi*32 + i*16 + fr)*64 + sa);
#pragma unroll
            for (int j = 0; j < 4; ++j)
                b[j] = *(const half8*)(Bs + (wj*64 + j*16 + fr)*64 + sa);
#pragma unroll
            for (int i = 0; i < 2; ++i)
#pragma unroll
                for (int j = 0; j < 4; ++j)
                    acc[i][j] = __builtin_amdgcn_mfma_f32_16x16x32_f16(a[i], b[j], acc[i][j], 0, 0, 0);
        }
        __syncthreads();
    }
    // GEMM done; LDS drained -> overlay epilogue structs.

#pragma unroll
    for (int i = 0; i < 2; ++i) {
#pragma unroll
        for (int r = 0; r < 4; ++r) {
            int pl = wi*32 + i*16 + quad*4 + r;
            int p = p0 + pl;
#pragma unroll
            for (int j = 0; j < 4; ++j) {
                int u = wj*64 + j*16 + fr;
                float v = acc[i][j][r];
                if (u < 36) {
                    sm.e.sdel[pl][u] = v + regb[(u>>2)*8 + (u&3)];
                } else if (u < 45) {
                    float z = v + clsb[u-36];
                    sm.e.scls[pl][u-36] = 1.f/(1.f + expf(-z));
                } else if (u < 99) {
                    lm_out[(size_t)p*54 + (u-45)] = v + lmb[u-45];
                }
            }
        }
    }
    __syncthreads();

    // fused decode: 64 positions x 9 anchors; per-block NMS seed max
    u64 local = 0ull;
    for (int t = tid; t < 64*9; t += 256) {
        int pl = t / 9, a = t - pl*9;
        int p = p0 + pl;
        int y = p / FW, x = p - FW*y;
        float cx = (x + 0.5f)*STRIDE, cy = (y + 0.5f)*STRIDE;
        const float rr[3] = {0.5f, 1.f, 2.f};
        const float ss[3] = {8.f, 16.f, 32.f};
        float r = rr[a/3], sv = ss[a - (a/3)*3];
        float h  = sqrtf(sv*sv/r)*STRIDE;
        float wvv = h * r;
        float x1a = cx - wvv*0.5f, y1a = cy - h*0.5f;
        float x2a = cx + wvv*0.5f, y2a = cy + h*0.5f;
        size_t n = (size_t)p*9 + a;
        float4 av = {x1a, y1a, x2a, y2a};
        *(float4*)(anch_out + 4*n) = av;
        bool valid = (x1a >= 0.f) && (y1a >= 0.f) && (x2a <= IMG) && (y2a <= IMG);

        float dx = sm.e.sdel[pl][a*4+0], dy = sm.e.sdel[pl][a*4+1];
        float dw = sm.e.sdel[pl][a*4+2], dh = sm.e.sdel[pl][a*4+3];
        float px = cx + wvv*dx, py = cy + h*dy;
        float pw = wvv*expf(dw), ph = h*expf(dh);
        float bx1 = px - pw*0.5f, by1 = py - ph*0.5f;
        float4 b;
        b.x = fminf(fmaxf(bx1, 0.f), IMG);
        b.y = fminf(fmaxf(by1, 0.f), IMG);
        b.z = fminf(fmaxf(bx1 + pw, 0.f), IMG);
        b.w = fminf(fmaxf(by1 + ph, 0.f), IMG);
        *(float4*)(boxes + 4*n) = b;
        float s = valid ? sm.e.scls[pl][a] : -1.f;
        s_arr[n] = s;
        u64 pk = pack_key(s, (int)n);
        local = local > pk ? local : pk;
    }
    local = wave_max64(local);
    if ((tid & 63) == 0) sm.e.red[tid >> 6] = local;
    __syncthreads();
    if (tid == 0) {
        u64 m = sm.e.red[0];
        m = m > sm.e.red[1] ? m : sm.e.red[1];
        m = m > sm.e.red[2] ? m : sm.e.red[2];
        m = m > sm.e.red[3] ? m : sm.e.red[3];
        blockmax[blockIdx.x] = m;
    }
}

// ---------------------------------------------------------------------------
// Lazy-max greedy NMS, ONE block, ONE launch (replaces 6). bm[] entries are
// UPPER BOUNDS of each block's current max (suppression only lowers scores).
// Round k: argmax over bounds; recompute that block's true max from the
// unmodified s_arr + winner list; validated (unchanged) -> global winner,
// else lower the bound and retry. Exact same winners/tie-breaks as before.
// ---------------------------------------------------------------------------
__global__ __launch_bounds__(256) void nms_lazy_kernel(
    const float* __restrict__ boxes, const float* __restrict__ s_arr,
    const u64* __restrict__ blockmax, float* __restrict__ rois)
{
    __shared__ u64 bm[HB];
    __shared__ u64 red[4];
    __shared__ float4 winbox[8];
    __shared__ int done;
    const int tid = threadIdx.x;
    for (int i = tid; i < HB; i += 256) bm[i] = blockmax[i];
    __syncthreads();

    for (int k = 0; k < 6; ++k) {
        for (int it = 0; it < 64; ++it) {
            // argmax over bounds
            u64 v = 0ull;
            for (int i = tid; i < HB; i += 256) v = v > bm[i] ? v : bm[i];
            v = wave_max64(v);
            if ((tid & 63) == 0) red[tid >> 6] = v;
            __syncthreads();
            u64 m = red[0];
            m = m > red[1] ? m : red[1];
            m = m > red[2] ? m : red[2];
            m = m > red[3] ? m : red[3];
            const unsigned n_top = ~(unsigned)(m & 0xFFFFFFFFull);
            const int bstar = n_top / HANCH;
            __syncthreads();                        // red WAR guard

            // recompute bstar's true max under winners[0..k-1]
            u64 loc = 0ull;
            for (int i = tid; i < HANCH; i += 256) {
                int n = bstar*HANCH + i;
                float s = s_arr[n];
                float4 b = *(const float4*)(boxes + (size_t)4*n);
                if (s > -1.f) {
                    float a2 = (b.z-b.x)*(b.w-b.y);
                    for (int j = 0; j < k; ++j) {
                        float4 wb = winbox[j];
                        float ix = fminf(wb.z,b.z)-fmaxf(wb.x,b.x);
                        float iy = fminf(wb.w,b.w)-fmaxf(wb.y,b.y);
                        float inter = fmaxf(ix,0.f)*fmaxf(iy,0.f);
                        float wa = (wb.z-wb.x)*(wb.w-wb.y);
                        float iou = inter/(wa+a2-inter+1e-9f);
                        if (iou > 0.5f) { s = -1.f; break; }
                    }
                }
                u64 pk = pack_key(s, n);
                loc = loc > pk ? loc : pk;
            }
            loc = wave_max64(loc);
            if ((tid & 63) == 0) red[tid >> 6] = loc;
            __syncthreads();
            u64 nm = red[0];
            nm = nm > red[1] ? nm : red[1];
            nm = nm > red[2] ? nm : red[2];
            nm = nm > red[3] ? nm : red[3];
            if (tid == 0) {
                bm[bstar] = nm;
                done = (nm == m);
                if (nm == m) {
                    float4 wb2 = *(const float4*)(boxes + (size_t)4*n_top);
                    winbox[k] = wb2;
                    *(float4*)(rois + 4*k) = wb2;
                }
            }
            __syncthreads();
            if (done) break;
        }
    }
}

// ---------------------------------------------------------------------------
// fallback fp32 path kernels (known-good round-1 structure)
// ---------------------------------------------------------------------------
__global__ __launch_bounds__(256) void conv1_kernel(
    const float* __restrict__ f, const float* __restrict__ w,
    const float* __restrict__ bias, float* __restrict__ xout)
{
    __shared__ float As2[32][66];
    __shared__ float Bs2[32][66];
    const int tid = threadIdx.x;
    const int nt = blockIdx.x;
    const int mt = blockIdx.y;
    const int p0 = mt*64, oc0 = nt*64;
    const int tm = tid & 15, tn = tid >> 4;
    const int kA = tid & 31, mA = tid >> 5;
    const int nB = tid & 63, kB = tid >> 6;
    int yv[8], xv[8];
#pragma unroll
    for (int it = 0; it < 8; ++it) {
        int p = p0 + mA + it*8;
        yv[it] = p / FW;
        xv[it] = p - yv[it]*FW;
    }
    float acc[4][4] = {};
    for (int tap = 0; tap < 9; ++tap) {
        const int ky = tap/3 - 1, kx = tap%3 - 1;
        for (int icb = 0; icb < 512; icb += 32) {
#pragma unroll
            for (int it = 0; it < 8; ++it) {
                int yy = yv[it] + ky, xx = xv[it] + kx;
                float v = 0.f;
                if ((unsigned)yy < (unsigned)FH && (unsigned)xx < (unsigned)FW)
                    v = f[(((yy*FW)+xx)<<9) + icb + kA];
                As2[kA][mA + it*8] = v;
            }
            const float* wp = w + ((size_t)(tap*512 + icb + kB))*512 + oc0 + nB;
#pragma unroll
            for (int it = 0; it < 8; ++it)
                Bs2[kB + it*4][nB] = wp[(size_t)it*4*512];
            __syncthreads();
#pragma unroll 8
            for (int kk = 0; kk < 32; ++kk) {
                float a0 = As2[kk][4*tm+0], a1 = As2[kk][4*tm+1],
                      a2 = As2[kk][4*tm+2], a3 = As2[kk][4*tm+3];
                float b0 = Bs2[kk][4*tn+0], b1 = Bs2[kk][4*tn+1],
                      b2 = Bs2[kk][4*tn+2], b3 = Bs2[kk][4*tn+3];
                acc[0][0] += a0*b0; acc[0][1] += a0*b1; acc[0][2] += a0*b2; acc[0][3] += a0*b3;
                acc[1][0] += a1*b0; acc[1][1] += a1*b1; acc[1][2] += a1*b2; acc[1][3] += a1*b3;
                acc[2][0] += a2*b0; acc[2][1] += a2*b1; acc[2][2] += a2*b2; acc[2][3] += a2*b3;
                acc[3][0] += a3*b0; acc[3][1] += a3*b1; acc[3][2] += a3*b2; acc[3][3] += a3*b3;
            }
            __syncthreads();
        }
    }
#pragma unroll
    for (int i = 0; i < 4; ++i) {
        int p = p0 + 4*tm + i;
        float4 o;
        float* op = &o.x;
#pragma unroll
        for (int j = 0; j < 4; ++j) {
            float v = acc[i][j] + bias[oc0 + 4*tn + j];
            op[j] = v > 0.f ? v : 0.f;
        }
        *(float4*)(xout + (size_t)p*512 + oc0 + 4*tn) = o;
    }
}

__global__ __launch_bounds__(256) void wprep_kernel(
    const float* __restrict__ regw, const float* __restrict__ clsw,
    const float* __restrict__ lmw, float* __restrict__ wT)
{
    int i = blockIdx.x*256 + threadIdx.x;
    if (i >= 99*512) return;
    int u = i >> 9, c = i & 511;
    float v;
    if (u < 36)      v = regw[c*72 + (u>>2)*8 + (u&3)];
    else if (u < 45) v = clsw[c*9 + (u-36)];
    else             v = lmw[c*54 + (u-45)];
    wT[i] = v;
}

__global__ __launch_bounds__(256) void heads_kernel(
    const float* __restrict__ x, const float* __restrict__ wT,
    const float* __restrict__ regb, const float* __restrict__ clsb,
    const float* __restrict__ lmb,
    float* __restrict__ lm_out, float* __restrict__ deltas,
    float* __restrict__ s_arr)
{
    __shared__ float xs[16*516];
    const int p0 = blockIdx.x * 16;
    const float4* src = (const float4*)(x + (size_t)p0*512);
    for (int i = threadIdx.x; i < 16*128; i += 256) {
        int row = i >> 7, c4 = i & 127;
        *(float4*)(xs + row*516 + c4*4) = src[row*128 + c4];
    }
    __syncthreads();
    for (int oi = threadIdx.x; oi < 99*16; oi += 256) {
        int ps = oi & 15, u = oi >> 4;
        const float4* wv = (const float4*)(wT + (u << 9));
        const float4* xv = (const float4*)(xs + ps*516);
        float acc = 0.f;
#pragma unroll 4
        for (int c = 0; c < 128; ++c) {
            float4 a = xv[c], b = wv[c];
            acc += a.x*b.x + a.y*b.y + a.z*b.z + a.w*b.w;
        }
        int p = p0 + ps;
        if (u < 36) {
            int aidx = u >> 2, r = u & 3;
            deltas[(size_t)(p*9 + aidx)*4 + r] = acc + regb[aidx*8 + r];
        } else if (u < 45) {
            float z = acc + clsb[u-36];
            s_arr[p*9 + (u-36)] = 1.f/(1.f + expf(-z));
        } else {
            lm_out[(size_t)p*54 + (u-45)] = acc + lmb[u-45];
        }
    }
}

__global__ __launch_bounds__(256) void decode_kernel(
    const float* __restrict__ deltas, float* __restrict__ s_arr,
    float* __restrict__ boxes, float* __restrict__ anch_out,
    u64* __restrict__ slot)
{
    int n = blockIdx.x*256 + threadIdx.x;
    if (n < 8) slot[n] = 0ull;
    if (n >= NANCH) return;
    int p = n / 9, a = n - 9*p;
    int y = p / FW, x = p - FW*y;
    float cx = (x + 0.5f)*STRIDE, cy = (y + 0.5f)*STRIDE;
    const float rr[3] = {0.5f, 1.f, 2.f};
    const float ss[3] = {8.f, 16.f, 32.f};
    float r = rr[a/3], sv = ss[a - (a/3)*3];
    float h  = sqrtf(sv*sv/r)*STRIDE;
    float wv = h * r;
    float x1a = cx - wv*0.5f, y1a = cy - h*0.5f;
    float x2a = cx + wv*0.5f, y2a = cy + h*0.5f;
    float4 av = {x1a, y1a, x2a, y2a};
    *(float4*)(anch_out + (size_t)4*n) = av;
    bool valid = (x1a >= 0.f) && (y1a >= 0.f) && (x2a <= IMG) && (y2a <= IMG);

    float4 d = *(const float4*)(deltas + (size_t)4*n);
    float px = cx + wv*d.x, py = cy + h*d.y;
    float pw = wv*expf(d.z), ph = h*expf(d.w);
    float bx1 = px - pw*0.5f, by1 = py - ph*0.5f;
    float4 b;
    b.x = fminf(fmaxf(bx1, 0.f), IMG);
    b.y = fminf(fmaxf(by1, 0.f), IMG);
    b.z = fminf(fmaxf(bx1 + pw, 0.f), IMG);
    b.w = fminf(fmaxf(by1 + ph, 0.f), IMG);
    *(float4*)(boxes + (size_t)4*n) = b;
    if (!valid) s_arr[n] = -1.f;
}

__global__ __launch_bounds__(256) void nms_iter_kernel(
    const float* __restrict__ boxes, float* __restrict__ s_arr,
    u64* __restrict__ slot, int k)
{
    __shared__ u64 red[4];
    int n = blockIdx.x*256 + threadIdx.x;
    float s = s_arr[n];
    if (k > 0) {
        unsigned int wn = ~(unsigned int)(slot[k-1] & 0xFFFFFFFFull);
        float4 wb = *(const float4*)(boxes + (size_t)4*wn);
        float4 b  = *(const float4*)(boxes + (size_t)4*n);
        float ix = fminf(wb.z, b.z) - fmaxf(wb.x, b.x);
        float iy = fminf(wb.w, b.w) - fmaxf(wb.y, b.y);
        float inter = fmaxf(ix, 0.f)*fmaxf(iy, 0.f);
        float a1 = (wb.z-wb.x)*(wb.w-wb.y);
        float a2 = (b.z-b.x)*(b.w-b.y);
        float iou = inter/(a1 + a2 - inter + 1e-9f);
        if (iou > 0.5f) { s = -1.f; s_arr[n] = -1.f; }
    }
    u64 packed = pack_key(s, n);
    packed = wave_max64(packed);
    if ((threadIdx.x & 63) == 0) red[threadIdx.x >> 6] = packed;
    __syncthreads();
    if (threadIdx.x == 0) {
        u64 m = red[0];
        m = m > red[1] ? m : red[1];
        m = m > red[2] ? m : red[2];
        m = m > red[3] ? m : red[3];
        atomicMax(&slot[k], m);
    }
}

__global__ void nms_fin_kernel(
    const float* __restrict__ boxes,
    const u64* __restrict__ slot, float* __restrict__ rois)
{
    int t = threadIdx.x;
    if (t < 6) {
        unsigned int n = ~(unsigned int)(slot[t] & 0xFFFFFFFFull);
        float4 b = *(const float4*)(boxes + (size_t)4*n);
        *(float4*)(rois + 4*t) = b;
    }
}

// ---------------------------------------------------------------------------
extern "C" void kernel_launch(void* const* d_in, const int* in_sizes, int n_in,
                              void* d_out, int out_size, void* d_ws, size_t ws_size,
                              hipStream_t stream)
{
    const float* f    = (const float*)d_in[0];
    const float* c1w  = (const float*)d_in[2];
    const float* c1b  = (const float*)d_in[3];
    const float* regw = (const float*)d_in[4];
    const float* regb = (const float*)d_in[5];
    const float* clsw = (const float*)d_in[6];
    const float* clsb = (const float*)d_in[7];
    const float* lmw  = (const float*)d_in[8];
    const float* lmb  = (const float*)d_in[9];

    float* out      = (float*)d_out;
    float* rois     = out;
    float* lm_out   = out + 24;
    float* anch_out = out + 24 + (size_t)NPOS*54;

    char* ws = (char*)d_ws;

    if (ws_size >= 62550016ull) {
        u64* blockmax = (u64*)ws;                                 //      3,200
        unsigned short* wh  = (unsigned short*)(ws + 4096);       //    131,072
        unsigned short* fph = (unsigned short*)(ws + 135168);     // 26,873,856
        unsigned short* wt  = (unsigned short*)(ws + 27009024);   //  4,718,592
        unsigned short* xh  = (unsigned short*)(ws + 31727616);   // 26,214,400
        float* boxes  = (float*)(ws + 57942016);                  //  3,686,400
        float* s_arr  = (float*)(ws + 61628416);                  //    921,600

        prep_kernel<<<PREP_GRID, 256, 0, stream>>>(f, c1w, regw, clsw, lmw,
                                                   fph, wt, wh);
        conv1_mfma_kernel<<<800, 256, 0, stream>>>(fph, wt, c1b, xh);
        heads_mfma_kernel<<<HB, 256, 0, stream>>>(xh, wh, regb, clsb, lmb,
                                                  lm_out, boxes, anch_out,
                                                  s_arr, blockmax);
        nms_lazy_kernel<<<1, 256, 0, stream>>>(boxes, s_arr, blockmax, rois);
    } else {
        u64* slot = (u64*)ws;
        float* wT     = (float*)(ws + 256);
        float* boxes  = (float*)(ws + 256 + 202752);
        float* deltas = (float*)(ws + 256 + 202752 + 3686400);
        float* s_arr  = (float*)(ws + 256 + 202752 + 2*3686400);
        float* x      = (float*)(ws + 256 + 202752 + 2*3686400 + 921600);

        wprep_kernel<<<(99*512 + 255)/256, 256, 0, stream>>>(regw, clsw, lmw, wT);
        conv1_kernel<<<dim3(8, 400), 256, 0, stream>>>(f, c1w, c1b, x);
        heads_kernel<<<NPOS/16, 256, 0, stream>>>(x, wT, regb, clsb, lmb,
                                                  lm_out, deltas, s_arr);
        decode_kernel<<<NANCH/256, 256, 0, stream>>>(deltas, s_arr, boxes,
                                                     anch_out, slot);
        for (int k = 0; k < 6; ++k)
            nms_iter_kernel<<<NANCH/256, 256, 0, stream>>>(boxes, s_arr, slot, k);
        nms_fin_kernel<<<1, 64, 0, stream>>>(boxes, slot, rois);
    }
}